// Round 1
// baseline (5648.325 us; speedup 1.0000x reference)
//
#include <hip/hip_runtime.h>
#include <math.h>

#define SEQ 2048
#define DIM 2048
#define NHEAD 16
#define HD 128
#define HIDDEN 5632
constexpr float EPS = 1e-6f;

// ---------------------------------------------------------------- rmsnorm
// One block (256 threads) per row of DIM=2048.
__global__ __launch_bounds__(256) void rmsnorm_kernel(const float* __restrict__ x,
                                                      const float* __restrict__ g,
                                                      float* __restrict__ out) {
    int row = blockIdx.x;
    const float* xr = x + (size_t)row * DIM;
    float* orow = out + (size_t)row * DIM;
    float ss = 0.f;
    for (int i = threadIdx.x; i < DIM; i += 256) {
        float v = xr[i];
        ss += v * v;
    }
    __shared__ float red[256];
    red[threadIdx.x] = ss;
    __syncthreads();
    for (int s = 128; s > 0; s >>= 1) {
        if (threadIdx.x < s) red[threadIdx.x] += red[threadIdx.x + s];
        __syncthreads();
    }
    float scale = rsqrtf(red[0] / (float)DIM + EPS);
    for (int i = threadIdx.x; i < DIM; i += 256) {
        orow[i] = xr[i] * scale * g[i];
    }
}

// ---------------------------------------------------------------- GEMM f32
// C[M,N] = A[M,K] @ B[K,N] with epilogue modes:
//   mode 0: C = AB
//   mode 1: C = AB + R        (residual add)
//   mode 2: C = silu(AB)
//   mode 3: C = C * AB        (SwiGLU gate: multiply into existing C)
// BM=BN=64, BK=16, 256 threads, 4x4 microtile per thread. M,N div by 64, K by 16.
#define BM 64
#define BN 64
#define BK 16
__global__ __launch_bounds__(256) void gemm_kernel(const float* __restrict__ A,
                                                   const float* __restrict__ B,
                                                   float* __restrict__ C,
                                                   int M, int N, int K,
                                                   const float* __restrict__ R,
                                                   int mode) {
    __shared__ float As[BM][BK];
    __shared__ float Bs[BK][BN];
    const int t = threadIdx.x;
    const int tx = t % 16;          // col group
    const int ty = t / 16;          // row group
    const int m0 = blockIdx.y * BM;
    const int n0 = blockIdx.x * BN;

    // staging indices: each thread loads one float4 of A-tile and one of B-tile
    const int ar = (t * 4) / BK, ac = (t * 4) % BK;   // 64x16 tile
    const int br = (t * 4) / BN, bc = (t * 4) % BN;   // 16x64 tile

    float acc[4][4] = {};

    for (int k0 = 0; k0 < K; k0 += BK) {
        float4 av = *(const float4*)(A + (size_t)(m0 + ar) * K + (k0 + ac));
        float4 bv = *(const float4*)(B + (size_t)(k0 + br) * N + (n0 + bc));
        *(float4*)&As[ar][ac] = av;
        *(float4*)&Bs[br][bc] = bv;
        __syncthreads();

#pragma unroll
        for (int kk = 0; kk < BK; ++kk) {
            float a0 = As[ty * 4 + 0][kk];
            float a1 = As[ty * 4 + 1][kk];
            float a2 = As[ty * 4 + 2][kk];
            float a3 = As[ty * 4 + 3][kk];
            float b0 = Bs[kk][tx * 4 + 0];
            float b1 = Bs[kk][tx * 4 + 1];
            float b2 = Bs[kk][tx * 4 + 2];
            float b3 = Bs[kk][tx * 4 + 3];
            acc[0][0] += a0 * b0; acc[0][1] += a0 * b1; acc[0][2] += a0 * b2; acc[0][3] += a0 * b3;
            acc[1][0] += a1 * b0; acc[1][1] += a1 * b1; acc[1][2] += a1 * b2; acc[1][3] += a1 * b3;
            acc[2][0] += a2 * b0; acc[2][1] += a2 * b1; acc[2][2] += a2 * b2; acc[2][3] += a2 * b3;
            acc[3][0] += a3 * b0; acc[3][1] += a3 * b1; acc[3][2] += a3 * b2; acc[3][3] += a3 * b3;
        }
        __syncthreads();
    }

#pragma unroll
    for (int i = 0; i < 4; ++i) {
#pragma unroll
        for (int j = 0; j < 4; ++j) {
            size_t idx = (size_t)(m0 + ty * 4 + i) * N + (n0 + tx * 4 + j);
            float v = acc[i][j];
            if (mode == 1) {
                v += R[idx];
                C[idx] = v;
            } else if (mode == 2) {
                C[idx] = v / (1.f + expf(-v));      // silu
            } else if (mode == 3) {
                C[idx] = C[idx] * v;                // gate multiply
            } else {
                C[idx] = v;
            }
        }
    }
}

// ---------------------------------------------------------------- RoPE (in-place on q and k)
// one thread per (s, h, pair)
__global__ __launch_bounds__(256) void rope_kernel(float* __restrict__ q, float* __restrict__ k,
                                                   const float* __restrict__ cs,
                                                   const float* __restrict__ sn) {
    int idx = blockIdx.x * 256 + threadIdx.x;           // 0 .. S*NH*HD/2
    int d2 = idx % (HD / 2);
    int rest = idx / (HD / 2);
    int h = rest % NHEAD;
    int s = rest / NHEAD;
    float c = cs[s * (HD / 2) + d2];
    float si = sn[s * (HD / 2) + d2];
    size_t base = ((size_t)s * NHEAD + h) * HD + 2 * d2;
    float qr = q[base], qi = q[base + 1];
    q[base]     = qr * c - qi * si;
    q[base + 1] = qr * si + qi * c;
    float kr = k[base], ki = k[base + 1];
    k[base]     = kr * c - ki * si;
    k[base + 1] = kr * si + ki * c;
}

// ---------------------------------------------------------------- attention
// One wave (64 lanes) per (query row s, head h). Online softmax; causal: t <= s.
// Lane holds dims 2*lane, 2*lane+1 of q / v / output.
__global__ __launch_bounds__(256) void attn_kernel(const float* __restrict__ q,
                                                   const float* __restrict__ k,
                                                   const float* __restrict__ v,
                                                   float* __restrict__ out) {
    int wave = (blockIdx.x * 256 + threadIdx.x) >> 6;
    int lane = threadIdx.x & 63;
    int h = wave % NHEAD;
    int s = wave / NHEAD;
    const float scale = 0.08838834764831845f;   // 1/sqrt(128)
    size_t qbase = ((size_t)s * NHEAD + h) * HD + 2 * lane;
    float2 qv = *(const float2*)(q + qbase);
    float q0 = qv.x * scale, q1 = qv.y * scale;

    float m = -INFINITY, l = 0.f, acc0 = 0.f, acc1 = 0.f;
    for (int t = 0; t <= s; ++t) {
        size_t kb = ((size_t)t * NHEAD + h) * HD + 2 * lane;
        float2 kv = *(const float2*)(k + kb);
        float p = q0 * kv.x + q1 * kv.y;
#pragma unroll
        for (int off = 32; off > 0; off >>= 1) p += __shfl_xor(p, off, 64);
        float mn = fmaxf(m, p);
        float alpha = __expf(m - mn);   // first iter: exp(-inf)=0
        float w = __expf(p - mn);
        float2 vv = *(const float2*)(v + kb);
        l = l * alpha + w;
        acc0 = acc0 * alpha + w * vv.x;
        acc1 = acc1 * alpha + w * vv.y;
        m = mn;
    }
    float inv_l = 1.f / l;
    out[qbase] = acc0 * inv_l;
    out[qbase + 1] = acc1 * inv_l;
}

// ---------------------------------------------------------------- launch
extern "C" void kernel_launch(void* const* d_in, const int* in_sizes, int n_in,
                              void* d_out, int out_size, void* d_ws, size_t ws_size,
                              hipStream_t stream) {
    const float* x      = (const float*)d_in[0];
    const float* f_cos  = (const float*)d_in[1];
    const float* f_sin  = (const float*)d_in[2];
    // d_in[3] = mask : ignored, causality computed analytically
    const float* wq     = (const float*)d_in[4];
    const float* wk     = (const float*)d_in[5];
    const float* wv     = (const float*)d_in[6];
    const float* wo     = (const float*)d_in[7];
    const float* w1     = (const float*)d_in[8];
    const float* w2     = (const float*)d_in[9];
    const float* w3     = (const float*)d_in[10];
    const float* g_attn = (const float*)d_in[11];
    const float* g_ffn  = (const float*)d_in[12];
    float* out = (float*)d_out;

    const size_t SD = (size_t)SEQ * DIM;          // 4M floats
    float* ws  = (float*)d_ws;
    float* xn  = ws;                // also reused as attn_out
    float* qb  = ws + SD;           // also reused as hn
    float* kb  = ws + 2 * SD;
    float* vb  = ws + 3 * SD;
    float* hb  = ws + 4 * SD;
    float* h1  = ws + 5 * SD;       // S x HIDDEN

    dim3 blk(256);
    dim3 g_sq(DIM / BN, SEQ / BM);            // 32 x 32
    dim3 g_ffn_grid(HIDDEN / BN, SEQ / BM);   // 88 x 32

    // 1. xn = rmsnorm(x, g_attn)
    rmsnorm_kernel<<<SEQ, blk, 0, stream>>>(x, g_attn, xn);
    // 2-4. q,k,v = xn @ {wq,wk,wv}
    gemm_kernel<<<g_sq, blk, 0, stream>>>(xn, wq, qb, SEQ, DIM, DIM, nullptr, 0);
    gemm_kernel<<<g_sq, blk, 0, stream>>>(xn, wk, kb, SEQ, DIM, DIM, nullptr, 0);
    gemm_kernel<<<g_sq, blk, 0, stream>>>(xn, wv, vb, SEQ, DIM, DIM, nullptr, 0);
    // 5. rope(q, k)
    rope_kernel<<<(SEQ * NHEAD * HD / 2) / 256, blk, 0, stream>>>(qb, kb, f_cos, f_sin);
    // 6. attn -> xn (reuse)
    attn_kernel<<<(SEQ * NHEAD * 64) / 256, blk, 0, stream>>>(qb, kb, vb, xn);
    // 7. h = attn @ wo + x
    gemm_kernel<<<g_sq, blk, 0, stream>>>(xn, wo, hb, SEQ, DIM, DIM, x, 1);
    // 8. hn = rmsnorm(h, g_ffn) -> qb (reuse)
    rmsnorm_kernel<<<SEQ, blk, 0, stream>>>(hb, g_ffn, qb);
    // 9. h1 = silu(hn @ w1)
    gemm_kernel<<<g_ffn_grid, blk, 0, stream>>>(qb, w1, h1, SEQ, HIDDEN, DIM, nullptr, 2);
    // 10. h1 *= hn @ w3
    gemm_kernel<<<g_ffn_grid, blk, 0, stream>>>(qb, w3, h1, SEQ, HIDDEN, DIM, nullptr, 3);
    // 11. out = h1 @ w2 + h
    gemm_kernel<<<g_sq, blk, 0, stream>>>(h1, w2, out, SEQ, DIM, HIDDEN, hb, 1);
}

// Round 2
// 4000.947 us; speedup vs baseline: 1.4117x; 1.4117x over previous
//
#include <hip/hip_runtime.h>
#include <math.h>

#define SEQ 2048
#define DIM 2048
#define NHEAD 16
#define HD 128
#define HIDDEN 5632
constexpr float EPS = 1e-6f;

// ---------------------------------------------------------------- rmsnorm
__global__ __launch_bounds__(256) void rmsnorm_kernel(const float* __restrict__ x,
                                                      const float* __restrict__ g,
                                                      float* __restrict__ out) {
    int row = blockIdx.x;
    const float* xr = x + (size_t)row * DIM;
    float* orow = out + (size_t)row * DIM;
    float ss = 0.f;
    for (int i = threadIdx.x; i < DIM; i += 256) {
        float v = xr[i];
        ss += v * v;
    }
    __shared__ float red[256];
    red[threadIdx.x] = ss;
    __syncthreads();
    for (int s = 128; s > 0; s >>= 1) {
        if (threadIdx.x < s) red[threadIdx.x] += red[threadIdx.x + s];
        __syncthreads();
    }
    float scale = rsqrtf(red[0] / (float)DIM + EPS);
    for (int i = threadIdx.x; i < DIM; i += 256) {
        orow[i] = xr[i] * scale * g[i];
    }
}

// ---------------------------------------------------------------- GEMM f32 (unchanged from R1)
#define BM 64
#define BN 64
#define BK 16
__global__ __launch_bounds__(256) void gemm_kernel(const float* __restrict__ A,
                                                   const float* __restrict__ B,
                                                   float* __restrict__ C,
                                                   int M, int N, int K,
                                                   const float* __restrict__ R,
                                                   int mode) {
    __shared__ float As[BM][BK];
    __shared__ float Bs[BK][BN];
    const int t = threadIdx.x;
    const int tx = t % 16;
    const int ty = t / 16;
    const int m0 = blockIdx.y * BM;
    const int n0 = blockIdx.x * BN;

    const int ar = (t * 4) / BK, ac = (t * 4) % BK;
    const int br = (t * 4) / BN, bc = (t * 4) % BN;

    float acc[4][4] = {};

    for (int k0 = 0; k0 < K; k0 += BK) {
        float4 av = *(const float4*)(A + (size_t)(m0 + ar) * K + (k0 + ac));
        float4 bv = *(const float4*)(B + (size_t)(k0 + br) * N + (n0 + bc));
        *(float4*)&As[ar][ac] = av;
        *(float4*)&Bs[br][bc] = bv;
        __syncthreads();

#pragma unroll
        for (int kk = 0; kk < BK; ++kk) {
            float a0 = As[ty * 4 + 0][kk];
            float a1 = As[ty * 4 + 1][kk];
            float a2 = As[ty * 4 + 2][kk];
            float a3 = As[ty * 4 + 3][kk];
            float b0 = Bs[kk][tx * 4 + 0];
            float b1 = Bs[kk][tx * 4 + 1];
            float b2 = Bs[kk][tx * 4 + 2];
            float b3 = Bs[kk][tx * 4 + 3];
            acc[0][0] += a0 * b0; acc[0][1] += a0 * b1; acc[0][2] += a0 * b2; acc[0][3] += a0 * b3;
            acc[1][0] += a1 * b0; acc[1][1] += a1 * b1; acc[1][2] += a1 * b2; acc[1][3] += a1 * b3;
            acc[2][0] += a2 * b0; acc[2][1] += a2 * b1; acc[2][2] += a2 * b2; acc[2][3] += a2 * b3;
            acc[3][0] += a3 * b0; acc[3][1] += a3 * b1; acc[3][2] += a3 * b2; acc[3][3] += a3 * b3;
        }
        __syncthreads();
    }

#pragma unroll
    for (int i = 0; i < 4; ++i) {
#pragma unroll
        for (int j = 0; j < 4; ++j) {
            size_t idx = (size_t)(m0 + ty * 4 + i) * N + (n0 + tx * 4 + j);
            float v = acc[i][j];
            if (mode == 1) {
                v += R[idx];
                C[idx] = v;
            } else if (mode == 2) {
                C[idx] = v / (1.f + expf(-v));
            } else if (mode == 3) {
                C[idx] = C[idx] * v;
            } else {
                C[idx] = v;
            }
        }
    }
}

// ---------------------------------------------------------------- RoPE
__global__ __launch_bounds__(256) void rope_kernel(float* __restrict__ q, float* __restrict__ k,
                                                   const float* __restrict__ cs,
                                                   const float* __restrict__ sn) {
    int idx = blockIdx.x * 256 + threadIdx.x;
    int d2 = idx % (HD / 2);
    int rest = idx / (HD / 2);
    int h = rest % NHEAD;
    int s = rest / NHEAD;
    float c = cs[s * (HD / 2) + d2];
    float si = sn[s * (HD / 2) + d2];
    size_t base = ((size_t)s * NHEAD + h) * HD + 2 * d2;
    float qr = q[base], qi = q[base + 1];
    q[base]     = qr * c - qi * si;
    q[base + 1] = qr * si + qi * c;
    float kr = k[base], ki = k[base + 1];
    k[base]     = kr * c - ki * si;
    k[base + 1] = kr * si + ki * c;
}

// ---------------------------------------------------------------- flash attention
// Block = 256 threads, handles one (head, 64-row Q tile). Loops over causal
// K/V tiles of 64 rows. K,V stored TRANSPOSED in LDS (d-major) so both the
// S-GEMM and PV-GEMM read contiguous float4 along the contraction dim.
// Pads: Qs 132, Kt/Vt 68, Ps 68 -> all ds_read_b128 at <=2-way (free).
__global__ __launch_bounds__(256) void flash_attn_kernel(const float* __restrict__ q,
                                                         const float* __restrict__ k,
                                                         const float* __restrict__ v,
                                                         float* __restrict__ out) {
    __shared__ float Qs[64][132];
    __shared__ float Kt[128][68];
    __shared__ float Vt[128][68];
    __shared__ float Ps[64][68];

    const int it = blockIdx.x;       // Q row-tile
    const int h  = blockIdx.y;       // head
    const int t  = threadIdx.x;
    const int tx = t & 15;
    const int ty = t >> 4;
    const int s0 = it * 64;
    const float scale = 0.08838834764831845f;   // 1/sqrt(128)

    // ---- stage Q tile (scaled), row-major, coalesced float4
#pragma unroll
    for (int u = 0; u < 8; ++u) {
        int vec = t + 256 * u;
        int r = vec >> 5, dv = vec & 31;
        float4 val = *(const float4*)(q + (size_t)(s0 + r) * DIM + h * HD + dv * 4);
        val.x *= scale; val.y *= scale; val.z *= scale; val.w *= scale;
        *(float4*)&Qs[r][dv * 4] = val;
    }

    float m[4], l[4], o[4][8];
#pragma unroll
    for (int i = 0; i < 4; ++i) {
        m[i] = -INFINITY;
        l[i] = 0.f;
#pragma unroll
        for (int d = 0; d < 8; ++d) o[i][d] = 0.f;
    }

    const int c0 = tx * 4;       // staging: 4 rows ; compute: 4 S-cols
    const int d0 = ty * 8;       // staging: 8 dims

    for (int jt = 0; jt <= it; ++jt) {
        const int tb = jt * 64;
        __syncthreads();     // previous iter's reads done before overwrite

        // ---- stage K,V tiles transposed via register transpose
        {
            float rg[4][8];
#pragma unroll
            for (int i = 0; i < 4; ++i) {
                const float* kp = k + (size_t)(tb + c0 + i) * DIM + h * HD + d0;
                float4 a = *(const float4*)kp;
                float4 b = *(const float4*)(kp + 4);
                rg[i][0] = a.x; rg[i][1] = a.y; rg[i][2] = a.z; rg[i][3] = a.w;
                rg[i][4] = b.x; rg[i][5] = b.y; rg[i][6] = b.z; rg[i][7] = b.w;
            }
#pragma unroll
            for (int dd = 0; dd < 8; ++dd)
                *(float4*)&Kt[d0 + dd][c0] = make_float4(rg[0][dd], rg[1][dd], rg[2][dd], rg[3][dd]);
#pragma unroll
            for (int i = 0; i < 4; ++i) {
                const float* vp = v + (size_t)(tb + c0 + i) * DIM + h * HD + d0;
                float4 a = *(const float4*)vp;
                float4 b = *(const float4*)(vp + 4);
                rg[i][0] = a.x; rg[i][1] = a.y; rg[i][2] = a.z; rg[i][3] = a.w;
                rg[i][4] = b.x; rg[i][5] = b.y; rg[i][6] = b.z; rg[i][7] = b.w;
            }
#pragma unroll
            for (int dd = 0; dd < 8; ++dd)
                *(float4*)&Vt[d0 + dd][c0] = make_float4(rg[0][dd], rg[1][dd], rg[2][dd], rg[3][dd]);
        }
        __syncthreads();

        // ---- S = Q K^T (64x64x128), thread owns rows ty*4+i, cols tx*4+j
        float sacc[4][4] = {};
        for (int kk = 0; kk < 128; kk += 4) {
            float4 qv[4], kv[4];
#pragma unroll
            for (int i = 0; i < 4; ++i) qv[i] = *(float4*)&Qs[ty * 4 + i][kk];
#pragma unroll
            for (int kq = 0; kq < 4; ++kq) kv[kq] = *(float4*)&Kt[kk + kq][c0];
#pragma unroll
            for (int i = 0; i < 4; ++i) {
                const float* qp = (const float*)&qv[i];
#pragma unroll
                for (int j = 0; j < 4; ++j) {
                    sacc[i][j] += qp[0] * ((const float*)&kv[0])[j]
                                + qp[1] * ((const float*)&kv[1])[j]
                                + qp[2] * ((const float*)&kv[2])[j]
                                + qp[3] * ((const float*)&kv[3])[j];
                }
            }
        }

        // ---- causal mask on diagonal tile
        if (jt == it) {
#pragma unroll
            for (int i = 0; i < 4; ++i)
#pragma unroll
                for (int j = 0; j < 4; ++j)
                    if (c0 + j > ty * 4 + i) sacc[i][j] = -1e30f;
        }

        // ---- online softmax (rows spread over 16 consecutive lanes)
#pragma unroll
        for (int i = 0; i < 4; ++i) {
            float mloc = fmaxf(fmaxf(sacc[i][0], sacc[i][1]), fmaxf(sacc[i][2], sacc[i][3]));
#pragma unroll
            for (int off = 1; off < 16; off <<= 1)
                mloc = fmaxf(mloc, __shfl_xor(mloc, off, 64));
            float mn = fmaxf(m[i], mloc);
            float alpha = __expf(m[i] - mn);
            float p0 = __expf(sacc[i][0] - mn);
            float p1 = __expf(sacc[i][1] - mn);
            float p2 = __expf(sacc[i][2] - mn);
            float p3 = __expf(sacc[i][3] - mn);
            float lloc = p0 + p1 + p2 + p3;
#pragma unroll
            for (int off = 1; off < 16; off <<= 1)
                lloc += __shfl_xor(lloc, off, 64);
            l[i] = l[i] * alpha + lloc;
            m[i] = mn;
#pragma unroll
            for (int d = 0; d < 8; ++d) o[i][d] *= alpha;
            *(float4*)&Ps[ty * 4 + i][c0] = make_float4(p0, p1, p2, p3);
        }
        __syncthreads();

        // ---- O += P V : thread owns rows ty*4+i, dims tx + 16*dq
        for (int c = 0; c < 64; c += 4) {
            float4 pv[4], vv[8];
#pragma unroll
            for (int i = 0; i < 4; ++i) pv[i] = *(float4*)&Ps[ty * 4 + i][c];
#pragma unroll
            for (int dq = 0; dq < 8; ++dq) vv[dq] = *(float4*)&Vt[tx + 16 * dq][c];
#pragma unroll
            for (int i = 0; i < 4; ++i) {
                const float* pp = (const float*)&pv[i];
#pragma unroll
                for (int dq = 0; dq < 8; ++dq) {
                    const float* vp = (const float*)&vv[dq];
                    o[i][dq] += pp[0] * vp[0] + pp[1] * vp[1] + pp[2] * vp[2] + pp[3] * vp[3];
                }
            }
        }
    }

    // ---- normalize + store
#pragma unroll
    for (int i = 0; i < 4; ++i) {
        float inv = 1.f / l[i];
        size_t rb = (size_t)(s0 + ty * 4 + i) * DIM + h * HD + tx;
#pragma unroll
        for (int dq = 0; dq < 8; ++dq)
            out[rb + 16 * dq] = o[i][dq] * inv;
    }
}

// ---------------------------------------------------------------- launch
extern "C" void kernel_launch(void* const* d_in, const int* in_sizes, int n_in,
                              void* d_out, int out_size, void* d_ws, size_t ws_size,
                              hipStream_t stream) {
    const float* x      = (const float*)d_in[0];
    const float* f_cos  = (const float*)d_in[1];
    const float* f_sin  = (const float*)d_in[2];
    // d_in[3] = mask : ignored, causality computed analytically
    const float* wq     = (const float*)d_in[4];
    const float* wk     = (const float*)d_in[5];
    const float* wv     = (const float*)d_in[6];
    const float* wo     = (const float*)d_in[7];
    const float* w1     = (const float*)d_in[8];
    const float* w2     = (const float*)d_in[9];
    const float* w3     = (const float*)d_in[10];
    const float* g_attn = (const float*)d_in[11];
    const float* g_ffn  = (const float*)d_in[12];
    float* out = (float*)d_out;

    const size_t SD = (size_t)SEQ * DIM;
    float* ws  = (float*)d_ws;
    float* xn  = ws;                // also reused as attn_out
    float* qb  = ws + SD;           // also reused as hn
    float* kb  = ws + 2 * SD;
    float* vb  = ws + 3 * SD;
    float* hb  = ws + 4 * SD;
    float* h1  = ws + 5 * SD;       // S x HIDDEN

    dim3 blk(256);
    dim3 g_sq(DIM / BN, SEQ / BM);
    dim3 g_ffn_grid(HIDDEN / BN, SEQ / BM);
    dim3 g_attn_grid(SEQ / 64, NHEAD);

    rmsnorm_kernel<<<SEQ, blk, 0, stream>>>(x, g_attn, xn);
    gemm_kernel<<<g_sq, blk, 0, stream>>>(xn, wq, qb, SEQ, DIM, DIM, nullptr, 0);
    gemm_kernel<<<g_sq, blk, 0, stream>>>(xn, wk, kb, SEQ, DIM, DIM, nullptr, 0);
    gemm_kernel<<<g_sq, blk, 0, stream>>>(xn, wv, vb, SEQ, DIM, DIM, nullptr, 0);
    rope_kernel<<<(SEQ * NHEAD * HD / 2) / 256, blk, 0, stream>>>(qb, kb, f_cos, f_sin);
    flash_attn_kernel<<<g_attn_grid, blk, 0, stream>>>(qb, kb, vb, xn);
    gemm_kernel<<<g_sq, blk, 0, stream>>>(xn, wo, hb, SEQ, DIM, DIM, x, 1);
    rmsnorm_kernel<<<SEQ, blk, 0, stream>>>(hb, g_ffn, qb);
    gemm_kernel<<<g_ffn_grid, blk, 0, stream>>>(qb, w1, h1, SEQ, HIDDEN, DIM, nullptr, 2);
    gemm_kernel<<<g_ffn_grid, blk, 0, stream>>>(qb, w3, h1, SEQ, HIDDEN, DIM, nullptr, 3);
    gemm_kernel<<<g_sq, blk, 0, stream>>>(h1, w2, out, SEQ, DIM, HIDDEN, hb, 1);
}

// Round 3
// 1402.857 us; speedup vs baseline: 4.0263x; 2.8520x over previous
//
#include <hip/hip_runtime.h>
#include <hip/hip_bf16.h>
#include <math.h>

#define SEQ 2048
#define DIM 2048
#define NHEAD 16
#define HD 128
#define HIDDEN 5632
#define QKVN 6144
constexpr float EPS = 1e-6f;

typedef __hip_bfloat16 bf16;
using short8  = __attribute__((ext_vector_type(8))) short;
using floatx4 = __attribute__((ext_vector_type(4))) float;

__device__ inline void gl_lds16(const void* g, void* l) {
    __builtin_amdgcn_global_load_lds((const __attribute__((address_space(1))) void*)g,
                                     (__attribute__((address_space(3))) void*)l, 16, 0, 0);
}

// ---------------------------------------------------------------- rmsnorm (f32 in, bf16 out)
__global__ __launch_bounds__(256) void rmsnorm_kernel(const float* __restrict__ x,
                                                      const float* __restrict__ g,
                                                      bf16* __restrict__ out) {
    int row = blockIdx.x;
    const float* xr = x + (size_t)row * DIM;
    bf16* orow = out + (size_t)row * DIM;
    float ss = 0.f;
    for (int i = threadIdx.x; i < DIM; i += 256) {
        float v = xr[i];
        ss += v * v;
    }
    __shared__ float red[256];
    red[threadIdx.x] = ss;
    __syncthreads();
    for (int s = 128; s > 0; s >>= 1) {
        if (threadIdx.x < s) red[threadIdx.x] += red[threadIdx.x + s];
        __syncthreads();
    }
    float scale = rsqrtf(red[0] / (float)DIM + EPS);
    for (int i = threadIdx.x; i < DIM; i += 256) {
        orow[i] = __float2bfloat16(xr[i] * scale * g[i]);
    }
}

// ---------------------------------------------------------------- weight cast+transpose
// in [K][N] f32  ->  out [N][K] bf16
__global__ __launch_bounds__(256) void cvt_t_kernel(const float* __restrict__ in,
                                                    bf16* __restrict__ out,
                                                    int K, int N) {
    __shared__ float tile[32][33];
    int nb = blockIdx.x * 32, kb = blockIdx.y * 32;
    int tx = threadIdx.x & 31, ty = threadIdx.x >> 5;   // 32 x 8
#pragma unroll
    for (int r = ty; r < 32; r += 8)
        tile[r][tx] = in[(size_t)(kb + r) * N + nb + tx];
    __syncthreads();
#pragma unroll
    for (int r = ty; r < 32; r += 8)
        out[(size_t)(nb + r) * K + kb + tx] = __float2bfloat16(tile[tx][r]);
}

// ---------------------------------------------------------------- bf16 MFMA GEMM (m97 structure)
// C[M][N](mode-dependent dtype) = A[M][K]bf16 @ Bt[N][K]bf16^T
// 128x128 tile, BK=32, 256 threads = 4 waves, each wave 64x64 (4x4 MFMA 16x16x32).
// MODE 0: bf16 C = AB          MODE 1: f32 C = AB + R
// MODE 2: bf16 C = silu(AB)    MODE 3: bf16 C = C * AB (in-place gate)
template <int MODE>
__global__ __launch_bounds__(256) void gemm_bf16(const bf16* __restrict__ A,
                                                 const bf16* __restrict__ Bt,
                                                 void* __restrict__ Cv,
                                                 const float* __restrict__ R,
                                                 int K, int ldc) {
    __shared__ bf16 Asm[128 * 32];
    __shared__ bf16 Bsm[128 * 32];
    const int t = threadIdx.x;
    const int m0 = blockIdx.y * 128;
    const int n0 = blockIdx.x * 128;
    const int lane = t & 63;
    const int wave = t >> 6;
    const int wr = wave >> 1, wc = wave & 1;
    const int quad = lane >> 4;
    const int l16 = lane & 15;

    floatx4 acc[4][4] = {};

    // staging map: thread t covers LDS bytes [t*16, t*16+16) of each half-tile
    const int ar = t >> 2;              // row 0..63
    const int ak = (t & 3) * 8;         // k elem offset
    const bf16* Ag = A + (size_t)(m0 + ar) * K + ak;
    const bf16* Bg = Bt + (size_t)(n0 + ar) * K + ak;
    bf16* Al = Asm + t * 8;
    bf16* Bl = Bsm + t * 8;
    const size_t half = (size_t)64 * K;

    for (int k0 = 0; k0 < K; k0 += 32) {
        __syncthreads();
        gl_lds16(Ag + k0, Al);
        gl_lds16(Ag + k0 + half, Al + 64 * 32);
        gl_lds16(Bg + k0, Bl);
        gl_lds16(Bg + k0 + half, Bl + 64 * 32);
        __syncthreads();

        short8 af[4], bfr[4];
#pragma unroll
        for (int i = 0; i < 4; ++i)
            af[i] = *(const short8*)(Asm + (wr * 64 + i * 16 + l16) * 32 + quad * 8);
#pragma unroll
        for (int j = 0; j < 4; ++j)
            bfr[j] = *(const short8*)(Bsm + (wc * 64 + j * 16 + l16) * 32 + quad * 8);
#pragma unroll
        for (int i = 0; i < 4; ++i)
#pragma unroll
            for (int j = 0; j < 4; ++j)
                acc[i][j] = __builtin_amdgcn_mfma_f32_16x16x32_bf16(af[i], bfr[j], acc[i][j], 0, 0, 0);
    }

#pragma unroll
    for (int i = 0; i < 4; ++i) {
#pragma unroll
        for (int j = 0; j < 4; ++j) {
#pragma unroll
            for (int r = 0; r < 4; ++r) {
                int m = m0 + wr * 64 + i * 16 + quad * 4 + r;
                int n = n0 + wc * 64 + j * 16 + l16;
                size_t idx = (size_t)m * ldc + n;
                float v = acc[i][j][r];
                if (MODE == 0) {
                    ((bf16*)Cv)[idx] = __float2bfloat16(v);
                } else if (MODE == 1) {
                    ((float*)Cv)[idx] = v + R[idx];
                } else if (MODE == 2) {
                    ((bf16*)Cv)[idx] = __float2bfloat16(v / (1.f + __expf(-v)));
                } else {
                    bf16* C = (bf16*)Cv;
                    C[idx] = __float2bfloat16(__bfloat162float(C[idx]) * v);
                }
            }
        }
    }
}

// ---------------------------------------------------------------- RoPE (in-place, bf16 qkv buffer)
__global__ __launch_bounds__(256) void rope_kernel(bf16* __restrict__ qkv,
                                                   const float* __restrict__ cs,
                                                   const float* __restrict__ sn) {
    int idx = blockIdx.x * 256 + threadIdx.x;
    int d2 = idx % (HD / 2);
    int rest = idx / (HD / 2);
    int h = rest % NHEAD;
    int s = rest / NHEAD;
    float c = cs[s * (HD / 2) + d2];
    float si = sn[s * (HD / 2) + d2];
    bf16* qp = qkv + (size_t)s * QKVN + h * HD + 2 * d2;
    bf16* kp = qp + DIM;
    float qr = __bfloat162float(qp[0]), qi = __bfloat162float(qp[1]);
    qp[0] = __float2bfloat16(qr * c - qi * si);
    qp[1] = __float2bfloat16(qr * si + qi * c);
    float kr = __bfloat162float(kp[0]), ki = __bfloat162float(kp[1]);
    kp[0] = __float2bfloat16(kr * c - ki * si);
    kp[1] = __float2bfloat16(kr * si + ki * c);
}

// ---------------------------------------------------------------- flash attention (bf16 in/out, f32 compute)
__global__ __launch_bounds__(256) void flash_attn_kernel(const bf16* __restrict__ qkv,
                                                         bf16* __restrict__ out) {
    __shared__ float Qs[64][132];
    __shared__ float Kt[128][68];
    __shared__ float Vt[128][68];
    __shared__ float Ps[64][68];

    const int it = blockIdx.x;
    const int h  = blockIdx.y;
    const int t  = threadIdx.x;
    const int tx = t & 15;
    const int ty = t >> 4;
    const int s0 = it * 64;
    const float scale = 0.08838834764831845f;

    union Cvt { uint4 u4; bf16 b[8]; };

    // ---- stage Q tile (scaled)
#pragma unroll
    for (int u = 0; u < 4; ++u) {
        int vec = t + 256 * u;              // 0..1023
        int r = vec >> 4, dv = vec & 15;    // row, 8-elem chunk
        Cvt cv;
        cv.u4 = *(const uint4*)(qkv + (size_t)(s0 + r) * QKVN + h * HD + dv * 8);
#pragma unroll
        for (int d = 0; d < 8; ++d)
            Qs[r][dv * 8 + d] = __bfloat162float(cv.b[d]) * scale;
    }

    float m[4], l[4], o[4][8];
#pragma unroll
    for (int i = 0; i < 4; ++i) {
        m[i] = -INFINITY;
        l[i] = 0.f;
#pragma unroll
        for (int d = 0; d < 8; ++d) o[i][d] = 0.f;
    }

    const int c0 = tx * 4;
    const int d0 = ty * 8;

    for (int jt = 0; jt <= it; ++jt) {
        const int tb = jt * 64;
        __syncthreads();

        {
            float rg[4][8];
#pragma unroll
            for (int i = 0; i < 4; ++i) {
                Cvt cv;
                cv.u4 = *(const uint4*)(qkv + (size_t)(tb + c0 + i) * QKVN + DIM + h * HD + d0);
#pragma unroll
                for (int d = 0; d < 8; ++d) rg[i][d] = __bfloat162float(cv.b[d]);
            }
#pragma unroll
            for (int dd = 0; dd < 8; ++dd)
                *(float4*)&Kt[d0 + dd][c0] = make_float4(rg[0][dd], rg[1][dd], rg[2][dd], rg[3][dd]);
#pragma unroll
            for (int i = 0; i < 4; ++i) {
                Cvt cv;
                cv.u4 = *(const uint4*)(qkv + (size_t)(tb + c0 + i) * QKVN + 2 * DIM + h * HD + d0);
#pragma unroll
                for (int d = 0; d < 8; ++d) rg[i][d] = __bfloat162float(cv.b[d]);
            }
#pragma unroll
            for (int dd = 0; dd < 8; ++dd)
                *(float4*)&Vt[d0 + dd][c0] = make_float4(rg[0][dd], rg[1][dd], rg[2][dd], rg[3][dd]);
        }
        __syncthreads();

        // ---- S = Q K^T
        float sacc[4][4] = {};
        for (int kk = 0; kk < 128; kk += 4) {
            float4 qv[4], kv[4];
#pragma unroll
            for (int i = 0; i < 4; ++i) qv[i] = *(float4*)&Qs[ty * 4 + i][kk];
#pragma unroll
            for (int kq = 0; kq < 4; ++kq) kv[kq] = *(float4*)&Kt[kk + kq][c0];
#pragma unroll
            for (int i = 0; i < 4; ++i) {
                const float* qp = (const float*)&qv[i];
#pragma unroll
                for (int j = 0; j < 4; ++j) {
                    sacc[i][j] += qp[0] * ((const float*)&kv[0])[j]
                                + qp[1] * ((const float*)&kv[1])[j]
                                + qp[2] * ((const float*)&kv[2])[j]
                                + qp[3] * ((const float*)&kv[3])[j];
                }
            }
        }

        if (jt == it) {
#pragma unroll
            for (int i = 0; i < 4; ++i)
#pragma unroll
                for (int j = 0; j < 4; ++j)
                    if (c0 + j > ty * 4 + i) sacc[i][j] = -1e30f;
        }

#pragma unroll
        for (int i = 0; i < 4; ++i) {
            float mloc = fmaxf(fmaxf(sacc[i][0], sacc[i][1]), fmaxf(sacc[i][2], sacc[i][3]));
#pragma unroll
            for (int off = 1; off < 16; off <<= 1)
                mloc = fmaxf(mloc, __shfl_xor(mloc, off, 64));
            float mn = fmaxf(m[i], mloc);
            float alpha = __expf(m[i] - mn);
            float p0 = __expf(sacc[i][0] - mn);
            float p1 = __expf(sacc[i][1] - mn);
            float p2 = __expf(sacc[i][2] - mn);
            float p3 = __expf(sacc[i][3] - mn);
            float lloc = p0 + p1 + p2 + p3;
#pragma unroll
            for (int off = 1; off < 16; off <<= 1)
                lloc += __shfl_xor(lloc, off, 64);
            l[i] = l[i] * alpha + lloc;
            m[i] = mn;
#pragma unroll
            for (int d = 0; d < 8; ++d) o[i][d] *= alpha;
            *(float4*)&Ps[ty * 4 + i][c0] = make_float4(p0, p1, p2, p3);
        }
        __syncthreads();

        for (int c = 0; c < 64; c += 4) {
            float4 pv[4], vv[8];
#pragma unroll
            for (int i = 0; i < 4; ++i) pv[i] = *(float4*)&Ps[ty * 4 + i][c];
#pragma unroll
            for (int dq = 0; dq < 8; ++dq) vv[dq] = *(float4*)&Vt[tx + 16 * dq][c];
#pragma unroll
            for (int i = 0; i < 4; ++i) {
                const float* pp = (const float*)&pv[i];
#pragma unroll
                for (int dq = 0; dq < 8; ++dq) {
                    const float* vp = (const float*)&vv[dq];
                    o[i][dq] += pp[0] * vp[0] + pp[1] * vp[1] + pp[2] * vp[2] + pp[3] * vp[3];
                }
            }
        }
    }

#pragma unroll
    for (int i = 0; i < 4; ++i) {
        float inv = 1.f / l[i];
        size_t rb = (size_t)(s0 + ty * 4 + i) * DIM + h * HD + tx;
#pragma unroll
        for (int dq = 0; dq < 8; ++dq)
            out[rb + 16 * dq] = __float2bfloat16(o[i][dq] * inv);
    }
}

// ---------------------------------------------------------------- launch
extern "C" void kernel_launch(void* const* d_in, const int* in_sizes, int n_in,
                              void* d_out, int out_size, void* d_ws, size_t ws_size,
                              hipStream_t stream) {
    const float* x      = (const float*)d_in[0];
    const float* f_cos  = (const float*)d_in[1];
    const float* f_sin  = (const float*)d_in[2];
    // d_in[3] = mask : ignored (causality analytic)
    const float* wq     = (const float*)d_in[4];
    const float* wk     = (const float*)d_in[5];
    const float* wv     = (const float*)d_in[6];
    const float* wo     = (const float*)d_in[7];
    const float* w1     = (const float*)d_in[8];
    const float* w2     = (const float*)d_in[9];
    const float* w3     = (const float*)d_in[10];
    const float* g_attn = (const float*)d_in[11];
    const float* g_ffn  = (const float*)d_in[12];
    float* out = (float*)d_out;

    // ---- workspace layout (bytes)
    char* base = (char*)d_ws;
    size_t off = 0;
    auto alloc = [&](size_t bytes) { void* p = base + off; off += (bytes + 255) & ~255ULL; return p; };
    bf16* qkvt = (bf16*)alloc((size_t)QKVN * DIM * 2);      // [6144][2048]
    bf16* wot  = (bf16*)alloc((size_t)DIM * DIM * 2);       // [2048][2048]
    bf16* w1t  = (bf16*)alloc((size_t)HIDDEN * DIM * 2);    // [5632][2048]
    bf16* w3t  = (bf16*)alloc((size_t)HIDDEN * DIM * 2);
    bf16* w2t  = (bf16*)alloc((size_t)DIM * HIDDEN * 2);    // [2048][5632]
    bf16* xbuf = (bf16*)alloc((size_t)SEQ * DIM * 2);       // xn / attn / hn
    bf16* qkv  = (bf16*)alloc((size_t)SEQ * QKVN * 2);      // [2048][6144]
    float* h   = (float*)alloc((size_t)SEQ * DIM * 4);
    bf16* t1   = (bf16*)alloc((size_t)SEQ * HIDDEN * 2);    // [2048][5632]

    dim3 blk(256);

    // ---- weight cast+transpose
    cvt_t_kernel<<<dim3(DIM / 32, DIM / 32), blk, 0, stream>>>(wq, qkvt, DIM, DIM);
    cvt_t_kernel<<<dim3(DIM / 32, DIM / 32), blk, 0, stream>>>(wk, qkvt + (size_t)DIM * DIM, DIM, DIM);
    cvt_t_kernel<<<dim3(DIM / 32, DIM / 32), blk, 0, stream>>>(wv, qkvt + (size_t)2 * DIM * DIM, DIM, DIM);
    cvt_t_kernel<<<dim3(DIM / 32, DIM / 32), blk, 0, stream>>>(wo, wot, DIM, DIM);
    cvt_t_kernel<<<dim3(HIDDEN / 32, DIM / 32), blk, 0, stream>>>(w1, w1t, DIM, HIDDEN);
    cvt_t_kernel<<<dim3(HIDDEN / 32, DIM / 32), blk, 0, stream>>>(w3, w3t, DIM, HIDDEN);
    cvt_t_kernel<<<dim3(DIM / 32, HIDDEN / 32), blk, 0, stream>>>(w2, w2t, HIDDEN, DIM);

    // ---- 1. xn = rmsnorm(x)
    rmsnorm_kernel<<<SEQ, blk, 0, stream>>>(x, g_attn, xbuf);
    // ---- 2. qkv = xn @ [wq|wk|wv]
    gemm_bf16<0><<<dim3(QKVN / 128, SEQ / 128), blk, 0, stream>>>(xbuf, qkvt, qkv, nullptr, DIM, QKVN);
    // ---- 3. rope
    rope_kernel<<<(SEQ * NHEAD * HD / 2) / 256, blk, 0, stream>>>(qkv, f_cos, f_sin);
    // ---- 4. attn -> xbuf
    flash_attn_kernel<<<dim3(SEQ / 64, NHEAD), blk, 0, stream>>>(qkv, xbuf);
    // ---- 5. h = attn @ wo + x
    gemm_bf16<1><<<dim3(DIM / 128, SEQ / 128), blk, 0, stream>>>(xbuf, wot, h, x, DIM, DIM);
    // ---- 6. hn = rmsnorm(h)
    rmsnorm_kernel<<<SEQ, blk, 0, stream>>>(h, g_ffn, xbuf);
    // ---- 7. t1 = silu(hn @ w1)
    gemm_bf16<2><<<dim3(HIDDEN / 128, SEQ / 128), blk, 0, stream>>>(xbuf, w1t, t1, nullptr, DIM, HIDDEN);
    // ---- 8. t1 *= hn @ w3
    gemm_bf16<3><<<dim3(HIDDEN / 128, SEQ / 128), blk, 0, stream>>>(xbuf, w3t, t1, nullptr, DIM, HIDDEN);
    // ---- 9. out = t1 @ w2 + h
    gemm_bf16<1><<<dim3(DIM / 128, SEQ / 128), blk, 0, stream>>>(t1, w2t, out, h, HIDDEN, DIM);
}

// Round 4
// 837.252 us; speedup vs baseline: 6.7463x; 1.6755x over previous
//
#include <hip/hip_runtime.h>
#include <hip/hip_bf16.h>
#include <math.h>

#define SEQ 2048
#define DIM 2048
#define NHEAD 16
#define HD 128
#define HIDDEN 5632
#define QKVN 6144
constexpr float EPS = 1e-6f;

typedef __hip_bfloat16 bf16;
using short8  = __attribute__((ext_vector_type(8))) short;
using short4v = __attribute__((ext_vector_type(4))) short;
using floatx4 = __attribute__((ext_vector_type(4))) float;

__device__ inline void gl_lds16(const void* g, void* l) {
    __builtin_amdgcn_global_load_lds((const __attribute__((address_space(1))) void*)g,
                                     (__attribute__((address_space(3))) void*)l, 16, 0, 0);
}

// ---------------------------------------------------------------- rmsnorm (f32 in, bf16 out)
__global__ __launch_bounds__(256) void rmsnorm_kernel(const float* __restrict__ x,
                                                      const float* __restrict__ g,
                                                      bf16* __restrict__ out) {
    int row = blockIdx.x;
    const float* xr = x + (size_t)row * DIM;
    bf16* orow = out + (size_t)row * DIM;
    float ss = 0.f;
    for (int i = threadIdx.x; i < DIM; i += 256) {
        float v = xr[i];
        ss += v * v;
    }
    __shared__ float red[256];
    red[threadIdx.x] = ss;
    __syncthreads();
    for (int s = 128; s > 0; s >>= 1) {
        if (threadIdx.x < s) red[threadIdx.x] += red[threadIdx.x + s];
        __syncthreads();
    }
    float scale = rsqrtf(red[0] / (float)DIM + EPS);
    for (int i = threadIdx.x; i < DIM; i += 256) {
        orow[i] = __float2bfloat16(xr[i] * scale * g[i]);
    }
}

// ---------------------------------------------------------------- weight cast+transpose
__global__ __launch_bounds__(256) void cvt_t_kernel(const float* __restrict__ in,
                                                    bf16* __restrict__ out,
                                                    int K, int N) {
    __shared__ float tile[32][33];
    int nb = blockIdx.x * 32, kb = blockIdx.y * 32;
    int tx = threadIdx.x & 31, ty = threadIdx.x >> 5;
#pragma unroll
    for (int r = ty; r < 32; r += 8)
        tile[r][tx] = in[(size_t)(kb + r) * N + nb + tx];
    __syncthreads();
#pragma unroll
    for (int r = ty; r < 32; r += 8)
        out[(size_t)(nb + r) * K + kb + tx] = __float2bfloat16(tile[tx][r]);
}

// ---------------------------------------------------------------- bf16 MFMA GEMM (m97 structure)
template <int MODE>
__global__ __launch_bounds__(256) void gemm_bf16(const bf16* __restrict__ A,
                                                 const bf16* __restrict__ Bt,
                                                 void* __restrict__ Cv,
                                                 const float* __restrict__ R,
                                                 int K, int ldc) {
    __shared__ bf16 Asm[128 * 32];
    __shared__ bf16 Bsm[128 * 32];
    const int t = threadIdx.x;
    const int m0 = blockIdx.y * 128;
    const int n0 = blockIdx.x * 128;
    const int lane = t & 63;
    const int wave = t >> 6;
    const int wr = wave >> 1, wc = wave & 1;
    const int quad = lane >> 4;
    const int l16 = lane & 15;

    floatx4 acc[4][4] = {};

    const int ar = t >> 2;
    const int ak = (t & 3) * 8;
    const bf16* Ag = A + (size_t)(m0 + ar) * K + ak;
    const bf16* Bg = Bt + (size_t)(n0 + ar) * K + ak;
    bf16* Al = Asm + t * 8;
    bf16* Bl = Bsm + t * 8;
    const size_t half = (size_t)64 * K;

    for (int k0 = 0; k0 < K; k0 += 32) {
        __syncthreads();
        gl_lds16(Ag + k0, Al);
        gl_lds16(Ag + k0 + half, Al + 64 * 32);
        gl_lds16(Bg + k0, Bl);
        gl_lds16(Bg + k0 + half, Bl + 64 * 32);
        __syncthreads();

        short8 af[4], bfr[4];
#pragma unroll
        for (int i = 0; i < 4; ++i)
            af[i] = *(const short8*)(Asm + (wr * 64 + i * 16 + l16) * 32 + quad * 8);
#pragma unroll
        for (int j = 0; j < 4; ++j)
            bfr[j] = *(const short8*)(Bsm + (wc * 64 + j * 16 + l16) * 32 + quad * 8);
#pragma unroll
        for (int i = 0; i < 4; ++i)
#pragma unroll
            for (int j = 0; j < 4; ++j)
                acc[i][j] = __builtin_amdgcn_mfma_f32_16x16x32_bf16(af[i], bfr[j], acc[i][j], 0, 0, 0);
    }

#pragma unroll
    for (int i = 0; i < 4; ++i) {
#pragma unroll
        for (int j = 0; j < 4; ++j) {
#pragma unroll
            for (int r = 0; r < 4; ++r) {
                int m = m0 + wr * 64 + i * 16 + quad * 4 + r;
                int n = n0 + wc * 64 + j * 16 + l16;
                size_t idx = (size_t)m * ldc + n;
                float v = acc[i][j][r];
                if (MODE == 0) {
                    ((bf16*)Cv)[idx] = __float2bfloat16(v);
                } else if (MODE == 1) {
                    ((float*)Cv)[idx] = v + R[idx];
                } else if (MODE == 2) {
                    ((bf16*)Cv)[idx] = __float2bfloat16(v / (1.f + __expf(-v)));
                } else {
                    bf16* C = (bf16*)Cv;
                    C[idx] = __float2bfloat16(__bfloat162float(C[idx]) * v);
                }
            }
        }
    }
}

// ---------------------------------------------------------------- RoPE (in-place, bf16 qkv buffer)
__global__ __launch_bounds__(256) void rope_kernel(bf16* __restrict__ qkv,
                                                   const float* __restrict__ cs,
                                                   const float* __restrict__ sn) {
    int idx = blockIdx.x * 256 + threadIdx.x;
    int d2 = idx % (HD / 2);
    int rest = idx / (HD / 2);
    int h = rest % NHEAD;
    int s = rest / NHEAD;
    float c = cs[s * (HD / 2) + d2];
    float si = sn[s * (HD / 2) + d2];
    bf16* qp = qkv + (size_t)s * QKVN + h * HD + 2 * d2;
    bf16* kp = qp + DIM;
    float qr = __bfloat162float(qp[0]), qi = __bfloat162float(qp[1]);
    qp[0] = __float2bfloat16(qr * c - qi * si);
    qp[1] = __float2bfloat16(qr * si + qi * c);
    float kr = __bfloat162float(kp[0]), ki = __bfloat162float(kp[1]);
    kp[0] = __float2bfloat16(kr * c - ki * si);
    kp[1] = __float2bfloat16(kr * si + ki * c);
}

// ---------------------------------------------------------------- MFMA flash attention
// Block = 256 thr = 4 waves; one (head, 64-row Q tile) per block. Wave w owns
// q-row strip 16w..16w+15. Q lives in registers as A-frags. K tile staged
// [key][dim] (B-frag direct), V staged transposed [dim][key] (PV B-frag),
// P round-trips C-layout -> LDS -> A-layout (m120 pattern), per-wave strip
// so no barrier between P write and read. LDS = 44 KB -> 3 blocks/CU.
// Causal balance: z<16 ? z : 47-z pairs blocks to constant total work.
__global__ __launch_bounds__(256, 3) void flash_attn_mfma(const bf16* __restrict__ qkv,
                                                          bf16* __restrict__ out) {
    __shared__ bf16 Ks[64][136];    // key-major, pad 8 (stride 272 B, 16B-mult)
    __shared__ bf16 Vt[128][72];    // dim-major, pad 8 (stride 144 B, 16B-mult)
    __shared__ bf16 Ps[64][72];

    const int b = blockIdx.x;
    const int h = b & (NHEAD - 1);
    const int z = b >> 4;
    const int it = (z < 16) ? z : 47 - z;
    const int t = threadIdx.x;
    const int lane = t & 63;
    const int w = t >> 6;
    const int quad = lane >> 4;
    const int l16 = lane & 15;
    const int s0 = it * 64;
    const float scale = 0.08838834764831845f;   // 1/sqrt(128)

    // ---- Q strip in registers: A-frag layout m=l16, k=quad*8+j
    short8 qreg[4];
    {
        const bf16* qrow = qkv + (size_t)(s0 + 16 * w + l16) * QKVN + h * HD + quad * 8;
#pragma unroll
        for (int ks = 0; ks < 4; ++ks)
            qreg[ks] = *(const short8*)(qrow + ks * 32);
    }

    floatx4 O[8] = {};          // 8 dim-tiles of 16x16, C layout
    float m_i[4], l_i[4];
#pragma unroll
    for (int r = 0; r < 4; ++r) { m_i[r] = -INFINITY; l_i[r] = 0.f; }

    const int vkg = t >> 5;     // V stage: keys vkg*8..+7
    const int vdg = t & 31;     // V stage: dims vdg*4..+3

    for (int jt = 0; jt <= it; ++jt) {
        const int tb = jt * 64;
        __syncthreads();

        // ---- stage K tile [64][128], coalesced 16B
#pragma unroll
        for (int u = 0; u < 4; ++u) {
            int vv = t + 256 * u;
            int kr = vv >> 4, kc = vv & 15;
            *(uint4*)&Ks[kr][kc * 8] =
                *(const uint4*)(qkv + (size_t)(tb + kr) * QKVN + DIM + h * HD + kc * 8);
        }
        // ---- stage V transposed via register transpose
        {
            short4v vr[8];
#pragma unroll
            for (int kk = 0; kk < 8; ++kk)
                vr[kk] = *(const short4v*)(qkv + (size_t)(tb + vkg * 8 + kk) * QKVN + 2 * DIM + h * HD + vdg * 4);
#pragma unroll
            for (int dd = 0; dd < 4; ++dd) {
                short8 wv;
#pragma unroll
                for (int kk = 0; kk < 8; ++kk) wv[kk] = vr[kk][dd];
                *(short8*)&Vt[vdg * 4 + dd][vkg * 8] = wv;
            }
        }
        __syncthreads();

        // ---- S = Q K^T : wave strip 16 x 64, 4 n-tiles x 4 k-steps
        floatx4 sacc[4] = {};
#pragma unroll
        for (int ks = 0; ks < 4; ++ks) {
            short8 kb[4];
#pragma unroll
            for (int nt = 0; nt < 4; ++nt)
                kb[nt] = *(const short8*)&Ks[nt * 16 + l16][ks * 32 + quad * 8];
#pragma unroll
            for (int nt = 0; nt < 4; ++nt)
                sacc[nt] = __builtin_amdgcn_mfma_f32_16x16x32_bf16(qreg[ks], kb[nt], sacc[nt], 0, 0, 0);
        }

        // ---- scale + causal mask + online softmax (row r = quad*4+r, col = nt*16+l16)
        float alpha[4];
#pragma unroll
        for (int r = 0; r < 4; ++r) {
            float mx = -INFINITY;
#pragma unroll
            for (int nt = 0; nt < 4; ++nt) {
                float s = sacc[nt][r] * scale;
                if (jt == it && (nt * 16 + l16) > (16 * w + quad * 4 + r)) s = -INFINITY;
                sacc[nt][r] = s;
                mx = fmaxf(mx, s);
            }
#pragma unroll
            for (int off = 1; off < 16; off <<= 1)
                mx = fmaxf(mx, __shfl_xor(mx, off, 64));
            float mn = fmaxf(m_i[r], mx);
            alpha[r] = __expf(m_i[r] - mn);
            float lsum = 0.f;
#pragma unroll
            for (int nt = 0; nt < 4; ++nt) {
                float e = __expf(sacc[nt][r] - mn);
                sacc[nt][r] = e;
                lsum += e;
            }
#pragma unroll
            for (int off = 1; off < 16; off <<= 1)
                lsum += __shfl_xor(lsum, off, 64);
            l_i[r] = l_i[r] * alpha[r] + lsum;
            m_i[r] = mn;
        }

        // ---- P (C-layout) -> LDS, own strip only (no cross-wave dependency)
#pragma unroll
        for (int nt = 0; nt < 4; ++nt)
#pragma unroll
            for (int r = 0; r < 4; ++r)
                Ps[16 * w + quad * 4 + r][nt * 16 + l16] = __float2bfloat16(sacc[nt][r]);

        // ---- rescale O, then O += P V
#pragma unroll
        for (int nt = 0; nt < 8; ++nt)
#pragma unroll
            for (int r = 0; r < 4; ++r)
                O[nt][r] *= alpha[r];

#pragma unroll
        for (int ks = 0; ks < 2; ++ks) {
            short8 pa = *(const short8*)&Ps[16 * w + l16][ks * 32 + quad * 8];
#pragma unroll
            for (int nt = 0; nt < 8; ++nt) {
                short8 vb = *(const short8*)&Vt[nt * 16 + l16][ks * 32 + quad * 8];
                O[nt] = __builtin_amdgcn_mfma_f32_16x16x32_bf16(pa, vb, O[nt], 0, 0, 0);
            }
        }
    }

    // ---- normalize + store (C layout: row=quad*4+r, col=l16)
#pragma unroll
    for (int r = 0; r < 4; ++r) {
        float inv = 1.f / l_i[r];
        bf16* orow = out + (size_t)(s0 + 16 * w + quad * 4 + r) * DIM + h * HD + l16;
#pragma unroll
        for (int nt = 0; nt < 8; ++nt)
            orow[nt * 16] = __float2bfloat16(O[nt][r] * inv);
    }
}

// ---------------------------------------------------------------- launch
extern "C" void kernel_launch(void* const* d_in, const int* in_sizes, int n_in,
                              void* d_out, int out_size, void* d_ws, size_t ws_size,
                              hipStream_t stream) {
    const float* x      = (const float*)d_in[0];
    const float* f_cos  = (const float*)d_in[1];
    const float* f_sin  = (const float*)d_in[2];
    // d_in[3] = mask : ignored (causality analytic)
    const float* wq     = (const float*)d_in[4];
    const float* wk     = (const float*)d_in[5];
    const float* wv     = (const float*)d_in[6];
    const float* wo     = (const float*)d_in[7];
    const float* w1     = (const float*)d_in[8];
    const float* w2     = (const float*)d_in[9];
    const float* w3     = (const float*)d_in[10];
    const float* g_attn = (const float*)d_in[11];
    const float* g_ffn  = (const float*)d_in[12];
    float* out = (float*)d_out;

    char* base = (char*)d_ws;
    size_t off = 0;
    auto alloc = [&](size_t bytes) { void* p = base + off; off += (bytes + 255) & ~255ULL; return p; };
    bf16* qkvt = (bf16*)alloc((size_t)QKVN * DIM * 2);
    bf16* wot  = (bf16*)alloc((size_t)DIM * DIM * 2);
    bf16* w1t  = (bf16*)alloc((size_t)HIDDEN * DIM * 2);
    bf16* w3t  = (bf16*)alloc((size_t)HIDDEN * DIM * 2);
    bf16* w2t  = (bf16*)alloc((size_t)DIM * HIDDEN * 2);
    bf16* xbuf = (bf16*)alloc((size_t)SEQ * DIM * 2);
    bf16* qkv  = (bf16*)alloc((size_t)SEQ * QKVN * 2);
    float* h   = (float*)alloc((size_t)SEQ * DIM * 4);
    bf16* t1   = (bf16*)alloc((size_t)SEQ * HIDDEN * 2);

    dim3 blk(256);

    cvt_t_kernel<<<dim3(DIM / 32, DIM / 32), blk, 0, stream>>>(wq, qkvt, DIM, DIM);
    cvt_t_kernel<<<dim3(DIM / 32, DIM / 32), blk, 0, stream>>>(wk, qkvt + (size_t)DIM * DIM, DIM, DIM);
    cvt_t_kernel<<<dim3(DIM / 32, DIM / 32), blk, 0, stream>>>(wv, qkvt + (size_t)2 * DIM * DIM, DIM, DIM);
    cvt_t_kernel<<<dim3(DIM / 32, DIM / 32), blk, 0, stream>>>(wo, wot, DIM, DIM);
    cvt_t_kernel<<<dim3(HIDDEN / 32, DIM / 32), blk, 0, stream>>>(w1, w1t, DIM, HIDDEN);
    cvt_t_kernel<<<dim3(HIDDEN / 32, DIM / 32), blk, 0, stream>>>(w3, w3t, DIM, HIDDEN);
    cvt_t_kernel<<<dim3(DIM / 32, HIDDEN / 32), blk, 0, stream>>>(w2, w2t, HIDDEN, DIM);

    rmsnorm_kernel<<<SEQ, blk, 0, stream>>>(x, g_attn, xbuf);
    gemm_bf16<0><<<dim3(QKVN / 128, SEQ / 128), blk, 0, stream>>>(xbuf, qkvt, qkv, nullptr, DIM, QKVN);
    rope_kernel<<<(SEQ * NHEAD * HD / 2) / 256, blk, 0, stream>>>(qkv, f_cos, f_sin);
    flash_attn_mfma<<<dim3(512), blk, 0, stream>>>(qkv, xbuf);
    gemm_bf16<1><<<dim3(DIM / 128, SEQ / 128), blk, 0, stream>>>(xbuf, wot, h, x, DIM, DIM);
    rmsnorm_kernel<<<SEQ, blk, 0, stream>>>(h, g_ffn, xbuf);
    gemm_bf16<2><<<dim3(HIDDEN / 128, SEQ / 128), blk, 0, stream>>>(xbuf, w1t, t1, nullptr, DIM, HIDDEN);
    gemm_bf16<3><<<dim3(HIDDEN / 128, SEQ / 128), blk, 0, stream>>>(xbuf, w3t, t1, nullptr, DIM, HIDDEN);
    gemm_bf16<1><<<dim3(DIM / 128, SEQ / 128), blk, 0, stream>>>(t1, w2t, out, h, HIDDEN, DIM);
}